// Round 16
// baseline (1050.723 us; speedup 1.0000x reference)
//
#include <hip/hip_runtime.h>
#include <hip/hip_fp16.h>
#include <math.h>

// ---------------------------------------------------------------------------
// Net_37512244363273: 5-level edge-conditioned graph conv + voxel pooling + FC
// Round 16: the 10-dispatch serial level-pipeline tail (~45+ us of launch
// gaps at the measured ~4-5 us/dispatch) is folded into ONE persistent
// kernel (mega_k): 512 blocks x 256 thr (launch_bounds(256,2) => 2 blocks/CU
// co-residency guaranteed; 12.5 KB LDS), phases P0..P9 = pool0, conv1s,
// pool1, coop2, pool2, coop3, pool3, coop4, pool4, fc, separated by a
// device-scope atomic grid barrier (threadfence release/acquire; counter
// zeroed by the in-graph memset). Phase bodies = verified round-15 kernels
// with grid-stride wrappers. K2-K6 (CSR builds, seg0/seg1 radix, conv0c,
// closs stats) unchanged. 16 -> 7 dispatches.
// Output: 80 log_softmax + closs = 81 floats.
// ---------------------------------------------------------------------------

#define NBUCK 8
#define TILES0 256                 // seg0 tiles (4096 edges each)
#define NB0    512                 // seg0 buckets (dst>>7, 128 nodes each)
#define IDXCAP 3072                // seg0 per-bucket index capacity
#define TILES1 64                  // seg1 tiles (4096 edges each)
#define NB1    512                 // seg1 buckets (dst>>5, 32 nodes each)
#define MBLK   512                 // mega kernel blocks (2/CU guaranteed)

struct SegArgs {
    const int* idx[10];
    int*       cnt[10];
    int*       rp [10];
    int*       out[10];
    int        n  [10];
    int        nb [10];
    int        shift[10];
    int        tstart[11];
};

struct ScanAux {
    int* tilesum;
    int* tileoff;
    int  sstart[11];
    int  T;
};

struct HArgs {
    const float* eattr[5];
    const float* w1[5];
    const float* b1[5];
    float*       H;
    int          E[5];
    int          bstart[6];
};

struct WArgs {
    const float* w2[5];
    const float* b2[5];
    const float* H;
    float*       sq;
    int          cico[5];
    int          E[5];
};

// ---------------------------------------------------------------------------
// K2: countA = cnt0 (256) | cnt1 (64) | hist_all (histBlocks) | hstats (rest)
// ---------------------------------------------------------------------------
__global__ __launch_bounds__(256) void countA_k(
    SegArgs a, HArgs ha, const int* __restrict__ dst0,
    const int* __restrict__ dst1, int* __restrict__ M, int* __restrict__ M1,
    int histBlocks)
{
    __shared__ int sh[NB0];
    int B = blockIdx.x;
    int t = threadIdx.x;

    if (B < TILES0) {                              // ---- cnt0 ----
        for (int u = t; u < NB0; u += 256) sh[u] = 0;
        __syncthreads();
        int base = B * 4096 + t;
        #pragma unroll
        for (int it = 0; it < 16; it++)
            atomicAdd(&sh[dst0[base + it * 256] >> 7], 1);
        __syncthreads();
        for (int u = t; u < NB0; u += 256) M[(size_t)B * NB0 + u] = sh[u];
        return;
    }
    B -= TILES0;
    if (B < TILES1) {                              // ---- cnt1 ----
        for (int u = t; u < NB1; u += 256) sh[u] = 0;
        __syncthreads();
        int base = B * 4096 + t;
        #pragma unroll
        for (int it = 0; it < 16; it++)
            atomicAdd(&sh[dst1[base + it * 256] >> 5], 1);
        __syncthreads();
        for (int u = t; u < NB1; u += 256) M1[(size_t)B * NB1 + u] = sh[u];
        return;
    }
    B -= TILES1;
    if (B < histBlocks) {                          // ---- hist_all (segs 2-9) ----
        int bucket = B % NBUCK;
        int T = B / NBUCK;
        int s = 0;
        while (s < 9 && T >= a.tstart[s + 1]) s++;
        int i = (T - a.tstart[s]) * 256 + t;
        if (i >= a.n[s]) return;
        int d = a.idx[s][i];
        if ((d >> a.shift[s]) != bucket) return;
        atomicAdd(&a.cnt[s][d], 1);
        return;
    }
    // ---- hstats (levels 1-4) ----
    int b = B - histBlocks;
    const int K = 32;
    int l = 0;
    while (l < 4 && b >= ha.bstart[l + 1]) l++;
    int bloc = b - ha.bstart[l];
    const float* ea = ha.eattr[l];
    float w1r[15], b1r[5];
    #pragma unroll
    for (int i = 0; i < 15; i++) w1r[i] = ha.w1[l][i];
    #pragma unroll
    for (int i = 0; i < 5; i++)  b1r[i] = ha.b1[l][i];
    float acc[20];
    #pragma unroll
    for (int i = 0; i < 20; i++) acc[i] = 0.f;
    int base = bloc * 256 * K + t;
    for (int it = 0; it < K; it++) {
        int e = base + it * 256;
        if (e < ha.E[l]) {
            float e0 = ea[e * 3], e1 = ea[e * 3 + 1], e2 = ea[e * 3 + 2];
            float h[5];
            #pragma unroll
            for (int k = 0; k < 5; k++)
                h[k] = tanhf(e0 * w1r[k] + e1 * w1r[5 + k] + e2 * w1r[10 + k] + b1r[k]);
            int p = 5;
            #pragma unroll
            for (int k = 0; k < 5; k++) {
                acc[k] += h[k];
                #pragma unroll
                for (int k2 = k; k2 < 5; k2++) acc[p++] += h[k] * h[k2];
            }
        }
    }
    float* red = (float*)sh;
    int wid = t >> 6, lane = t & 63;
    #pragma unroll
    for (int v = 0; v < 20; v++) {
        float s = acc[v];
        #pragma unroll
        for (int o = 32; o; o >>= 1) s += __shfl_down(s, o);
        if (lane == 0) red[wid * 20 + v] = s;
    }
    __syncthreads();
    if (t < 20)
        atomicAdd(&ha.H[l * 20 + t],
                  red[t] + red[20 + t] + red[40 + t] + red[60 + t]);
}

// ---------------------------------------------------------------------------
// K3: scanP1 = colscan0 (NB0) | colscan1 (NB1) | scanA (rest)
// ---------------------------------------------------------------------------
__global__ __launch_bounds__(256) void scanP1_k(
    SegArgs a, ScanAux x, const int* __restrict__ M, int* __restrict__ M2,
    int* __restrict__ colTotal, const int* __restrict__ M1,
    int* __restrict__ M21, int* __restrict__ ct1)
{
    __shared__ int sc[256];
    int B = blockIdx.x;
    int t = threadIdx.x;

    if (B < NB0) {                                 // ---- colscan0 ----
        int v = M[(size_t)t * NB0 + B];
        sc[t] = v;
        __syncthreads();
        for (int d = 1; d < 256; d <<= 1) {
            int u = (t >= d) ? sc[t - d] : 0;
            __syncthreads();
            sc[t] += u;
            __syncthreads();
        }
        M2[(size_t)t * NB0 + B] = sc[t] - v;
        if (t == 255) colTotal[B] = sc[255];
        return;
    }
    B -= NB0;
    if (B < NB1) {                                 // ---- colscan1 (wave 0) ----
        if (t >= 64) return;
        int v = M1[(size_t)t * NB1 + B];
        int val = v;
        #pragma unroll
        for (int d = 1; d < 64; d <<= 1) {
            int u = __shfl_up(val, d);
            if (t >= d) val += u;
        }
        M21[(size_t)t * NB1 + B] = val - v;
        if (t == 63) ct1[B] = val;
        return;
    }
    // ---- scanA (segs 2-9) ----
    int b = B - NB1;
    int s = 0;
    while (s < 9 && b >= x.sstart[s + 1]) s++;
    int tloc = b - x.sstart[s];
    int nb = a.nb[s];
    const int* cnt = a.cnt[s];
    int i0 = tloc * 4096 + t * 16;
    int sum = 0;
    #pragma unroll
    for (int k = 0; k < 16; k++) {
        int i = i0 + k;
        if (i < nb) sum += cnt[i];
    }
    #pragma unroll
    for (int o = 32; o; o >>= 1) sum += __shfl_down(sum, o);
    if ((t & 63) == 0) sc[t >> 6] = sum;
    __syncthreads();
    if (t == 0)
        x.tilesum[b] = sc[0] + sc[1] + sc[2] + sc[3];
}

// ---------------------------------------------------------------------------
// K4: scanP2 = bktscan0 (blk 0) | scanB (blk 1) | bktscan1 (blk 2)
// ---------------------------------------------------------------------------
__global__ __launch_bounds__(512) void scanP2_k(
    SegArgs a, ScanAux x, const int* __restrict__ colTotal,
    int* __restrict__ bucketStart, const int* __restrict__ ct1,
    int* __restrict__ bs1)
{
    __shared__ int sc[NB0];
    int t = threadIdx.x;
    if (blockIdx.x == 0) {                         // ---- bktscan0 ----
        int v = colTotal[t];
        sc[t] = v;
        __syncthreads();
        for (int d = 1; d < NB0; d <<= 1) {
            int u = (t >= d) ? sc[t - d] : 0;
            __syncthreads();
            sc[t] += u;
            __syncthreads();
        }
        bucketStart[t] = sc[t] - v;
        if (t == NB0 - 1) bucketStart[NB0] = sc[NB0 - 1];
        return;
    }
    if (blockIdx.x == 2) {                         // ---- bktscan1 ----
        int v = ct1[t];
        sc[t] = v;
        __syncthreads();
        for (int d = 1; d < NB1; d <<= 1) {
            int u = (t >= d) ? sc[t - d] : 0;
            __syncthreads();
            sc[t] += u;
            __syncthreads();
        }
        bs1[t] = sc[t] - v;
        if (t == NB1 - 1) bs1[NB1] = sc[NB1 - 1];
        return;
    }
    // ---- scanB (wave 0) ----
    if (t >= 64) return;
    int lane = t;
    int orig = (lane < x.T) ? x.tilesum[lane] : 0;
    int val = orig;
    #pragma unroll
    for (int d = 1; d < 64; d <<= 1) {
        int v = __shfl_up(val, d);
        if (lane >= d) val += v;
    }
    int excl = val - orig;
    int s = 0;
    while (s < 9 && lane >= x.sstart[s + 1]) s++;
    int segExcl = __shfl(excl, x.sstart[s]);
    if (lane < x.T) {
        x.tileoff[lane] = excl - segExcl;
        if (lane == x.sstart[s + 1] - 1)
            a.rp[s][a.nb[s]] = val - segExcl;
    }
}

// ---------------------------------------------------------------------------
// K5: scanP3 = scanC (sx.T) | part0 (TILES0) | part1 (TILES1)
// ---------------------------------------------------------------------------
__global__ __launch_bounds__(256) void scanP3_k(
    SegArgs a, ScanAux x,
    const int* __restrict__ src, const int* __restrict__ dst,
    const float* __restrict__ ea, const float* __restrict__ x0,
    const int* __restrict__ M2, const int* __restrict__ bucketStart,
    float4* __restrict__ pay2,
    const float* __restrict__ w1, const float* __restrict__ b1,
    float* __restrict__ H0,
    const int* __restrict__ src1, const int* __restrict__ dst1,
    const float* __restrict__ ea1, const int* __restrict__ M21,
    const int* __restrict__ bs1, float4* __restrict__ pay1)
{
    __shared__ int   shi[NB0];
    __shared__ float shf[100];
    int B = blockIdx.x;
    int t = threadIdx.x;

    if (B < x.T) {                                 // ---- scanC (segs 2-9) ----
        int s = 0;
        while (s < 9 && B >= x.sstart[s + 1]) s++;
        int tloc = B - x.sstart[s];
        int nb = a.nb[s];
        const int* cnt = a.cnt[s];
        int* rp = a.rp[s];
        int i0 = tloc * 4096 + t * 16;
        int v[16];
        int sum = 0;
        #pragma unroll
        for (int k = 0; k < 16; k++) {
            int i = i0 + k;
            v[k] = (i < nb) ? cnt[i] : 0;
            sum += v[k];
        }
        int acc = sum;
        shi[t] = acc;
        __syncthreads();
        for (int d = 1; d < 256; d <<= 1) {
            int t2 = (t >= d) ? shi[t - d] : 0;
            __syncthreads();
            acc += t2;
            shi[t] = acc;
            __syncthreads();
        }
        int running = x.tileoff[B] + (acc - sum);
        #pragma unroll
        for (int k = 0; k < 16; k++) {
            int i = i0 + k;
            if (i < nb) rp[i] = running;
            running += v[k];
        }
        return;
    }
    B -= x.T;
    if (B < TILES0) {                              // ---- part0 ----
        int tile = B;
        for (int u = t; u < NB0; u += 256)
            shi[u] = bucketStart[u] + M2[(size_t)tile * NB0 + u];
        if (t < 15) shf[t] = w1[t];
        if (t >= 32 && t < 37) shf[15 + t - 32] = b1[t - 32];
        __syncthreads();

        float acc[20];
        #pragma unroll
        for (int i = 0; i < 20; i++) acc[i] = 0.f;

        int base = tile * 4096 + t;
        #pragma unroll 4
        for (int it = 0; it < 16; it++) {
            int i = base + it * 256;
            int d = dst[i];
            float e0 = ea[i * 3], e1 = ea[i * 3 + 1], e2 = ea[i * 3 + 2];
            float h[5];
            #pragma unroll
            for (int k = 0; k < 5; k++)
                h[k] = tanhf(e0 * shf[k] + e1 * shf[5 + k] + e2 * shf[10 + k] + shf[15 + k]);
            int p = 5;
            #pragma unroll
            for (int k = 0; k < 5; k++) {
                acc[k] += h[k];
                #pragma unroll
                for (int k2 = k; k2 < 5; k2++) acc[p++] += h[k] * h[k2];
            }
            float xv = x0[src[i]];
            union HU { __half2 h2; float f; } p01, p23;
            p01.h2 = __floats2half2_rn(h[0], h[1]);
            p23.h2 = __floats2half2_rn(h[2], h[3]);
            unsigned wbits = ((unsigned)d << 16) |
                             (unsigned)__half_as_ushort(__float2half_rn(h[4]));
            int ps = atomicAdd(&shi[d >> 7], 1);
            pay2[ps] = make_float4(xv, p01.f, p23.f, __uint_as_float(wbits));
        }

        int wid = t >> 6, lane = t & 63;
        #pragma unroll
        for (int v = 0; v < 20; v++) {
            float s = acc[v];
            #pragma unroll
            for (int o = 32; o; o >>= 1) s += __shfl_down(s, o);
            if (lane == 0) shf[20 + wid * 20 + v] = s;
        }
        __syncthreads();
        if (t < 20)
            atomicAdd(&H0[t], shf[20 + t] + shf[40 + t] + shf[60 + t] + shf[80 + t]);
        return;
    }
    // ---- part1: record = (key=(dst<<16)|src, ea0, ea1, ea2) ----
    int tile = B - TILES0;
    for (int u = t; u < NB1; u += 256)
        shi[u] = bs1[u] + M21[(size_t)tile * NB1 + u];
    __syncthreads();
    int base = tile * 4096 + t;
    #pragma unroll 4
    for (int it = 0; it < 16; it++) {
        int i = base + it * 256;
        int d = dst1[i];
        int key = (d << 16) | src1[i];
        float e0 = ea1[i * 3], e1 = ea1[i * 3 + 1], e2 = ea1[i * 3 + 2];
        int ps = atomicAdd(&shi[d >> 5], 1);
        pay1[ps] = make_float4(__int_as_float(key), e0, e1, e2);
    }
}

// ---------------------------------------------------------------------------
// K6: scatC = scatter_all (histBlocks) | conv0c (NB0) | wstats (5) |
//             bucket1 (NB1)
// ---------------------------------------------------------------------------
__global__ __launch_bounds__(256) void scatC_k(
    SegArgs a, WArgs wa, int histBlocks,
    const float4* __restrict__ pay2, const int* __restrict__ bucketStart,
    const float* __restrict__ w2, const float* __restrict__ b2,
    const float* __restrict__ root, const float* __restrict__ bias,
    const float* __restrict__ x, float* __restrict__ y,
    const float4* __restrict__ pay1, const int* __restrict__ bs1,
    int* __restrict__ rp1, float4* __restrict__ rec1)
{
    __shared__ float wsm[96];
    __shared__ int hist[128], st[128], cur[128];
    __shared__ int idxL[IDXCAP];
    int B = blockIdx.x;
    int t = threadIdx.x;

    if (B < histBlocks) {                          // ---- scatter_all ----
        int bucket = B % NBUCK;
        int T = B / NBUCK;
        int s = 0;
        while (s < 9 && T >= a.tstart[s + 1]) s++;
        int i = (T - a.tstart[s]) * 256 + t;
        if (i >= a.n[s]) return;
        int d = a.idx[s][i];
        if ((d >> a.shift[s]) != bucket) return;
        int p = atomicSub(&a.cnt[s][d], 1) - 1;
        a.out[s][a.rp[s][d] + p] = i;
        return;
    }
    B -= histBlocks;
    if (B < NB0) {                                 // ---- conv0c ----
        if (t < 60) wsm[t] = w2[t];
        else if (t >= 64  && t < 76)  wsm[60 + t - 64]  = b2[t - 64];
        else if (t >= 128 && t < 140) wsm[72 + t - 128] = root[t - 128];
        else if (t >= 192 && t < 204) wsm[84 + t - 192] = bias[t - 192];
        if (t < 128) hist[t] = 0;
        __syncthreads();

        int lo = bucketStart[B], hi = bucketStart[B + 1];
        int bin0 = B << 7;
        const float* payw = (const float*)pay2;
        for (int j = lo + t; j < hi; j += 256) {
            int rel = (int)(__float_as_uint(payw[4 * j + 3]) >> 16) - bin0;
            atomicAdd(&hist[rel], 1);
        }
        __syncthreads();
        if (t < 128) st[t] = hist[t];
        __syncthreads();
        for (int d = 1; d < 128; d <<= 1) {
            int u = (t < 128 && t >= d) ? st[t - d] : 0;
            __syncthreads();
            if (t < 128) st[t] += u;
            __syncthreads();
        }
        if (t < 128) cur[t] = st[t] - hist[t];
        __syncthreads();
        for (int j = lo + t; j < hi; j += 256) {
            int rel = (int)(__float_as_uint(payw[4 * j + 3]) >> 16) - bin0;
            int p = atomicAdd(&cur[rel], 1);
            idxL[p] = j;
        }
        __syncthreads();

        if (t < 128) {
            int v = bin0 + t;
            int deg = hist[t];
            int s0 = st[t] - deg;
            float S0 = 0.f, S1 = 0.f, S2 = 0.f, S3 = 0.f, S4 = 0.f, S5 = 0.f;
            for (int jj = s0; jj < s0 + deg; jj++) {
                float4 R = pay2[idxL[jj]];
                union HU { float f; __half2 h2; } a01, a23;
                a01.f = R.y; a23.f = R.z;
                unsigned wbits = __float_as_uint(R.w);
                float xv = R.x;
                S0 += xv;
                S1 += __low2float(a01.h2)  * xv;
                S2 += __high2float(a01.h2) * xv;
                S3 += __low2float(a23.h2)  * xv;
                S4 += __high2float(a23.h2) * xv;
                S5 += __half2float(__ushort_as_half((unsigned short)(wbits & 0xffffu))) * xv;
            }
            float inv = 1.f / fmaxf((float)deg, 1.f);
            float xv = x[v];
            #pragma unroll
            for (int o = 0; o < 12; o++) {
                float msg = wsm[60 + o] * S0 + wsm[o] * S1 + wsm[12 + o] * S2 +
                            wsm[24 + o] * S3 + wsm[36 + o] * S4 + wsm[48 + o] * S5;
                y[v * 12 + o] = msg * inv + xv * wsm[72 + o] + wsm[84 + o];
            }
        }
        return;
    }
    B -= NB0;
    if (B < 5) {                                   // ---- wstats (wave 0) ----
        if (t >= 64) return;
        int l = B;
        const float* w2l = wa.w2[l];
        const float* b2l = wa.b2[l];
        int cico = wa.cico[l];
        float d[21];
        #pragma unroll
        for (int i = 0; i < 21; i++) d[i] = 0.f;
        for (int u = t; u < cico; u += 64) {
            float b = b2l[u];
            float w[5];
            #pragma unroll
            for (int k = 0; k < 5; k++) w[k] = w2l[k * cico + u];
            int p = 0;
            #pragma unroll
            for (int k = 0; k < 5; k++) {
                #pragma unroll
                for (int k2 = k; k2 < 5; k2++) d[p++] += w[k] * w[k2];
            }
            #pragma unroll
            for (int k = 0; k < 5; k++) d[15 + k] += b * w[k];
            d[20] += b * b;
        }
        #pragma unroll
        for (int i = 0; i < 21; i++) {
            #pragma unroll
            for (int off = 32; off; off >>= 1) d[i] += __shfl_down(d[i], off);
        }
        if (t == 0) {
            const float* H1 = wa.H + l * 20;
            const float* H2 = H1 + 5;
            float sq = (float)wa.E[l] * d[20];
            #pragma unroll
            for (int k = 0; k < 5; k++) sq += 2.f * d[15 + k] * H1[k];
            int p = 0;
            #pragma unroll
            for (int k = 0; k < 5; k++) {
                #pragma unroll
                for (int k2 = k; k2 < 5; k2++) {
                    sq += ((k == k2) ? 1.f : 2.f) * d[p] * H2[p];
                    p++;
                }
            }
            wa.sq[l] = sq;
        }
        return;
    }
    // ---- bucket1: sort bucket's records by dst, emit rp1 + rec1 ----
    int b = B - 5;
    int lo = bs1[b], hi = bs1[b + 1];
    int bin0 = b << 5;
    if (t < 32) hist[t] = 0;
    __syncthreads();
    const float* payw = (const float*)pay1;
    for (int j = lo + t; j < hi; j += 256) {
        int rel = (int)(__float_as_uint(payw[4 * j]) >> 16) - bin0;
        atomicAdd(&hist[rel], 1);
    }
    __syncthreads();
    if (t < 32) {
        int v = hist[t];
        int val = v;
        #pragma unroll
        for (int d = 1; d < 32; d <<= 1) {
            int u = __shfl_up(val, d);
            if (t >= d) val += u;
        }
        st[t] = val - v;
        cur[t] = lo + val - v;
        rp1[bin0 + t] = lo + val - v;
        if (b == NB1 - 1 && t == 31) rp1[NB1 * 32] = hi;
    }
    __syncthreads();
    for (int j = lo + t; j < hi; j += 256) {
        float4 R = pay1[j];
        int rel = (int)(__float_as_uint(R.x) >> 16) - bin0;
        int p = atomicAdd(&cur[rel], 1);
        rec1[p] = R;
    }
}

// ---------------------------------------------------------------------------
// mega_k device phases
// ---------------------------------------------------------------------------
__device__ __forceinline__ void grid_barrier(int* bar, int target) {
    __syncthreads();
    if (threadIdx.x == 0) {
        __threadfence();
        atomicAdd(bar, 1);
        while (atomicAdd(bar, 0) < target) __builtin_amdgcn_s_sleep(2);
        __threadfence();
    }
    __syncthreads();
}

__device__ void pool_phase(int NN, int CO,
    const int* crp, const int* cnid, const float* y, const float* pos,
    float* xn, float* pn)
{
    int total = NN * (CO + 3);
    for (int t = blockIdx.x * 256 + threadIdx.x; t < total; t += MBLK * 256) {
        int c = t / (CO + 3), o = t % (CO + 3);
        int r0 = crp[c], r1 = crp[c + 1];
        int d = r1 - r0;
        if (o < CO) {
            float m = -INFINITY;
            for (int j = r0; j < r1; j++)
                m = fmaxf(m, y[(size_t)cnid[j] * CO + o]);
            if (d == 0 || !isfinite(m)) m = 0.f;
            xn[c * (CO + 3) + o] = m;
        } else {
            int k = o - CO;
            float sum = 0.f;
            for (int j = r0; j < r1; j++)
                sum += pos[cnid[j] * 3 + k];
            float pm = sum / fmaxf((float)d, 1.f);
            xn[c * (CO + 3) + CO + k] = pm;
            pn[c * 3 + k] = pm;
        }
    }
}

template<int CI, int CO>
__device__ void coop_phase(int N,
    const int* rp, const int* eid, const int* src, const float* eattr,
    const float* w1, const float* b1, const float* w2, const float* b2,
    const float* root, const float* bias, const float* x, float* y,
    char* smem)
{
    constexpr int CH = 48, CICO = CI * CO;
    float* w1s = (float*)smem;                    // 20
    int*   eb  = (int*)(smem + 96);               // 48
    int*   svb = eb + 48;                         // 48
    float* hb  = (float*)(svb + 48);              // 288
    float* xs  = hb + 288;                        // 48*CI
    float* S   = xs + 48 * CI;                    // 6*CI
    int t = threadIdx.x;

    for (int v = blockIdx.x; v < N; v += MBLK) {
        if (t < 20) w1s[t] = (t < 15) ? w1[t] : b1[t - 15];
        int r0 = rp[v], r1 = rp[v + 1];
        int d  = r1 - r0;
        float acc = 0.f;

        for (int c0 = r0; c0 < r1; c0 += CH) {
            int cn = min(CH, r1 - c0);
            if (t < cn) {
                int e = eid[c0 + t];
                eb[t]  = e;
                svb[t] = src[e];
                hb[t * 6] = 1.f;
            }
            __syncthreads();
            if (t < cn * 5) {
                int j = t / 5, k = t % 5;
                int e = eb[j];
                float e0 = eattr[e * 3], e1 = eattr[e * 3 + 1], e2 = eattr[e * 3 + 2];
                hb[j * 6 + 1 + k] =
                    tanhf(e0 * w1s[k] + e1 * w1s[5 + k] + e2 * w1s[10 + k] + w1s[15 + k]);
            }
            for (int u = t; u < cn * CI; u += 256)
                xs[u] = x[(size_t)svb[u / CI] * CI + (u % CI)];
            __syncthreads();
            if (t < 6 * CI) {
                int i = t / 6, k6 = t % 6;
                for (int j = 0; j < cn; j++)
                    acc += hb[j * 6 + k6] * xs[j * CI + i];
            }
            __syncthreads();
        }

        if (t < 6 * CI) S[t] = acc;
        __syncthreads();

        if (t < CO) {
            float m = 0.f;
            for (int i = 0; i < CI; i++) {
                m += b2[i * CO + t] * S[i * 6];
                #pragma unroll
                for (int k = 0; k < 5; k++)
                    m += w2[k * CICO + i * CO + t] * S[i * 6 + 1 + k];
            }
            m /= fmaxf((float)d, 1.f);
            for (int i = 0; i < CI; i++)
                m += x[(size_t)v * CI + i] * root[i * CO + t];
            y[(size_t)v * CO + t] = m + bias[t];
        }
        __syncthreads();
    }
}

__device__ void conv1s_phase(int N,
    const int* rp, const float4* rec,
    const float* w1, const float* b1, const float* w2, const float* b2,
    const float* root, const float* bias, const float* x, float* y,
    char* smem)
{
    constexpr int CI = 15, CO = 20, CH = 48, CICO = CI * CO;
    float4* recb = (float4*)smem;                 // 48 (768 B)
    int*    svb  = (int*)(smem + 768);            // 48
    float*  hb   = (float*)(svb + 48);            // 288
    float*  xs   = hb + 288;                      // 720
    float*  S    = xs + 720;                      // 90
    float*  w1s  = S + 90;                        // 20
    int t = threadIdx.x;

    for (int v = blockIdx.x; v < N; v += MBLK) {
        if (t < 20) w1s[t] = (t < 15) ? w1[t] : b1[t - 15];
        int r0 = rp[v], r1 = rp[v + 1];
        int d  = r1 - r0;
        float acc = 0.f;

        for (int c0 = r0; c0 < r1; c0 += CH) {
            int cn = min(CH, r1 - c0);
            if (t < cn) {
                float4 R = rec[c0 + t];
                recb[t] = R;
                svb[t]  = (int)(__float_as_uint(R.x) & 0xffffu);
                hb[t * 6] = 1.f;
            }
            __syncthreads();
            if (t < cn * 5) {
                int j = t / 5, k = t % 5;
                float e0 = recb[j].y, e1 = recb[j].z, e2 = recb[j].w;
                hb[j * 6 + 1 + k] =
                    tanhf(e0 * w1s[k] + e1 * w1s[5 + k] + e2 * w1s[10 + k] + w1s[15 + k]);
            }
            for (int u = t; u < cn * CI; u += 256)
                xs[u] = x[(size_t)svb[u / CI] * CI + (u % CI)];
            __syncthreads();
            if (t < 6 * CI) {
                int i = t / 6, k6 = t % 6;
                for (int j = 0; j < cn; j++)
                    acc += hb[j * 6 + k6] * xs[j * CI + i];
            }
            __syncthreads();
        }

        if (t < 6 * CI) S[t] = acc;
        __syncthreads();

        if (t < CO) {
            float m = 0.f;
            for (int i = 0; i < CI; i++) {
                m += b2[i * CO + t] * S[i * 6];
                #pragma unroll
                for (int k = 0; k < 5; k++)
                    m += w2[k * CICO + i * CO + t] * S[i * 6 + 1 + k];
            }
            m /= fmaxf((float)d, 1.f);
            for (int i = 0; i < CI; i++)
                m += x[(size_t)v * CI + i] * root[i * CO + t];
            y[(size_t)v * CO + t] = m + bias[t];
        }
        __syncthreads();
    }
}

__device__ void fc_phase(
    const float* x5, const float* fc_w, const float* fc_b,
    const float* sq, float* out, char* smem)
{
    float* feat  = (float*)smem;                  // 3008
    float* logit = feat + 3008;                   // 80
    float* roff  = logit + 80;                    // 8
    int t = threadIdx.x;
    for (int u = t; u < 8 * 376; u += 256) feat[u] = x5[u];
    __syncthreads();
    if (t < 80) {
        int b = t / 10, j = t % 10;
        float acc = fc_b[j];
        for (int k = 0; k < 376; k++) acc += feat[b * 376 + k] * fc_w[k * 10 + j];
        logit[t] = acc;
    }
    __syncthreads();
    if (t < 8) {
        float m = -1e30f;
        for (int j = 0; j < 10; j++) m = fmaxf(m, logit[t * 10 + j]);
        float ssum = 0.f;
        for (int j = 0; j < 10; j++) ssum += expf(logit[t * 10 + j] - m);
        roff[t] = m + logf(ssum);
    }
    __syncthreads();
    if (t < 80) out[t] = logit[t] - roff[t / 10];
    if (t == 0) {
        float closs = 0.f;
        closs += sq[0] * (1.0f / 12582912.0f);
        closs += sq[1] * (1.0f / 78643200.0f);
        closs += sq[2] * (1.0f / 42205184.0f);
        closs += sq[3] * (1.0f / 18284544.0f);
        closs += sq[4] * (1.0f / 7028736.0f);
        out[80] = closs;
    }
}

// ---------------------------------------------------------------------------
// mega_k: the whole level pipeline + fc as one persistent kernel.
// 512 blocks x 256 thr, 2 blocks/CU guaranteed (launch_bounds(256,2),
// 12.5 KB LDS). bar zeroed by the in-graph memset every call.
// ---------------------------------------------------------------------------
struct MegaArgs {
    const int*   crp[5];
    const int*   cnid[5];
    const int*   rp[5];       // rp[1]=rec1-based; rp[2..4]=eid-based
    const int*   eid[5];
    const float4* rec1;
    const int*   src[5];
    const float* eattr[5];
    const float* w1[5], *b1[5], *w2[5], *b2[5], *root[5], *bias[5];
    const float* pos0;
    float*       xn[5];
    float*       pn[5];
    float*       y;
    const float* fc_w, *fc_b, *sq;
    float*       out;
    int*         bar;
};

__global__ __launch_bounds__(256, 2) void mega_k(MegaArgs m)
{
    __shared__ __align__(16) char smem[12544];
    int tgt = MBLK;

    // P0: pool0 (y from conv0c -> xn0, pn0)
    pool_phase(16384, 12, m.crp[0], m.cnid[0], m.y, m.pos0, m.xn[0], m.pn[0]);
    grid_barrier(m.bar, tgt); tgt += MBLK;
    // P1: conv1s (L1)
    conv1s_phase(16384, m.rp[1], m.rec1, m.w1[1], m.b1[1], m.w2[1], m.b2[1],
                 m.root[1], m.bias[1], m.xn[0], m.y, smem);
    grid_barrier(m.bar, tgt); tgt += MBLK;
    // P2: pool1
    pool_phase(4096, 20, m.crp[1], m.cnid[1], m.y, m.pn[0], m.xn[1], m.pn[1]);
    grid_barrier(m.bar, tgt); tgt += MBLK;
    // P3: coop L2
    coop_phase<23, 28>(4096, m.rp[2], m.eid[2], m.src[2], m.eattr[2],
                       m.w1[2], m.b1[2], m.w2[2], m.b2[2], m.root[2],
                       m.bias[2], m.xn[1], m.y, smem);
    grid_barrier(m.bar, tgt); tgt += MBLK;
    // P4: pool2
    pool_phase(1024, 28, m.crp[2], m.cnid[2], m.y, m.pn[1], m.xn[2], m.pn[2]);
    grid_barrier(m.bar, tgt); tgt += MBLK;
    // P5: coop L3
    coop_phase<31, 36>(1024, m.rp[3], m.eid[3], m.src[3], m.eattr[3],
                       m.w1[3], m.b1[3], m.w2[3], m.b2[3], m.root[3],
                       m.bias[3], m.xn[2], m.y, smem);
    grid_barrier(m.bar, tgt); tgt += MBLK;
    // P6: pool3
    pool_phase(256, 36, m.crp[3], m.cnid[3], m.y, m.pn[2], m.xn[3], m.pn[3]);
    grid_barrier(m.bar, tgt); tgt += MBLK;
    // P7: coop L4
    coop_phase<39, 44>(256, m.rp[4], m.eid[4], m.src[4], m.eattr[4],
                       m.w1[4], m.b1[4], m.w2[4], m.b2[4], m.root[4],
                       m.bias[4], m.xn[3], m.y, smem);
    grid_barrier(m.bar, tgt); tgt += MBLK;
    // P8: pool4
    pool_phase(64, 44, m.crp[4], m.cnid[4], m.y, m.pn[3], m.xn[4], m.pn[4]);
    grid_barrier(m.bar, tgt); tgt += MBLK;
    // P9: fc (block 0 only)
    if (blockIdx.x == 0)
        fc_phase(m.xn[4], m.fc_w, m.fc_b, m.sq, m.out, smem);
}

// ---------------------------------------------------------------------------

extern "C" void kernel_launch(void* const* d_in, const int* in_sizes, int n_in,
                              void* d_out, int out_size, void* d_ws, size_t ws_size,
                              hipStream_t stream)
{
    static const int NSa[6] = {65536, 16384, 4096, 1024, 256, 64};
    static const int ESa[5] = {1048576, 262144, 65536, 16384, 4096};
    static const int COa[5] = {12, 20, 28, 36, 44};
    static const int CIa[5] = {1, 15, 23, 31, 39};

    const float* x0   = (const float*)d_in[0];
    const float* pos0 = (const float*)d_in[1];

    // ---- workspace layout (words), ~38 MB total ----
    int* wsw = (int*)d_ws;
    size_t off = 0;
    auto alw = [&](size_t n) -> size_t {
        size_t p = off; off += (n + 63) & ~(size_t)63; return p;
    };
    size_t degO[5], cdegO[5];
    for (int l = 2; l < 5; l++) degO[l]  = alw(NSa[l]);
    for (int l = 0; l < 5; l++) cdegO[l] = alw(NSa[l + 1]);
    size_t HO   = alw(100);
    size_t barO = alw(16);                                // grid barrier
    size_t zeroWords = off;                               // zero-init to here
    size_t rpO[5], crpO[5], eidO[5], cnidO[5];
    rpO[1] = alw(NSa[1] + 1);
    for (int l = 2; l < 5; l++) rpO[l]  = alw(NSa[l] + 1);
    for (int l = 0; l < 5; l++) crpO[l] = alw(NSa[l + 1] + 1);
    for (int l = 2; l < 5; l++) eidO[l] = alw(ESa[l]);
    for (int l = 0; l < 5; l++) cnidO[l] = alw(NSa[l]);
    size_t tsO  = alw(64);
    size_t toO  = alw(64);
    size_t MO   = alw((size_t)TILES0 * NB0);
    size_t M2O  = alw((size_t)TILES0 * NB0);
    size_t ctO  = alw(NB0);
    size_t bsO  = alw(NB0 + 1);
    size_t payO = alw((size_t)ESa[0] * 4);
    size_t M1O  = alw((size_t)TILES1 * NB1);
    size_t M21O = alw((size_t)TILES1 * NB1);
    size_t ct1O = alw(NB1);
    size_t bs1O = alw(NB1 + 1);
    size_t pay1O = alw((size_t)ESa[1] * 4);
    size_t rec1O = alw((size_t)ESa[1] * 4);
    size_t yO   = alw((size_t)65536 * 12);
    size_t sqO  = alw(8);
    size_t xnO[5], pnO[5];
    for (int l = 0; l < 5; l++) xnO[l] = alw((size_t)NSa[l + 1] * (COa[l] + 3));
    for (int l = 0; l < 5; l++) pnO[l] = alw((size_t)NSa[l + 1] * 3);

    hipMemsetAsync(d_ws, 0, zeroWords * 4, stream);

    // ---- segs 2-9 descriptor (edge segs 2-4 + cluster segs 0-4) ----
    SegArgs sa{};
    int nseg = 0;
    for (int l = 2; l < 5; l++) {
        sa.idx[nseg] = (const int*)d_in[3 + 10 * l];
        sa.cnt[nseg] = wsw + degO[l];
        sa.rp [nseg] = wsw + rpO[l];
        sa.out[nseg] = wsw + eidO[l];
        sa.n  [nseg] = ESa[l];
        sa.nb [nseg] = NSa[l];
        nseg++;
    }
    for (int l = 0; l < 5; l++) {
        sa.idx[nseg] = (const int*)d_in[5 + 10 * l];
        sa.cnt[nseg] = wsw + cdegO[l];
        sa.rp [nseg] = wsw + crpO[l];
        sa.out[nseg] = wsw + cnidO[l];
        sa.n  [nseg] = NSa[l];
        sa.nb [nseg] = NSa[l + 1];
        nseg++;
    }
    ScanAux sx{};
    int tiles = 0, btiles = 0;
    for (int s = 0; s < nseg; s++) {
        int lg = 31 - __builtin_clz(sa.nb[s]);
        sa.shift[s] = lg - 3;
        sa.tstart[s] = tiles;
        tiles += (sa.n[s] + 255) / 256;
        sx.sstart[s] = btiles;
        btiles += (sa.nb[s] + 4095) / 4096;
    }
    for (int s = nseg; s <= 10; s++) {
        sa.tstart[s] = tiles;
        sx.sstart[s] = btiles;
        if (s < 10) {
            sa.idx[s] = sa.idx[nseg - 1]; sa.cnt[s] = sa.cnt[nseg - 1];
            sa.rp[s] = sa.rp[nseg - 1];   sa.out[s] = sa.out[nseg - 1];
            sa.n[s] = 0; sa.nb[s] = 8; sa.shift[s] = 0;
        }
    }
    sx.T = btiles;
    sx.tilesum = wsw + tsO;
    sx.tileoff = wsw + toO;
    int histBlocks = tiles * NBUCK;

    float4* pay2 = (float4*)(wsw + payO);
    float4* pay1 = (float4*)(wsw + pay1O);
    float4* rec1 = (float4*)(wsw + rec1O);
    float*  Hp   = (float*)(wsw + HO);

    HArgs ha{};
    int bs = 0;
    ha.bstart[0] = 0;
    ha.eattr[0] = (const float*)d_in[4];
    ha.w1[0] = (const float*)d_in[6];
    ha.b1[0] = (const float*)d_in[7];
    ha.E[0] = 0;
    for (int l = 1; l < 5; l++) {
        ha.eattr[l] = (const float*)d_in[4 + 10 * l];
        ha.w1[l]    = (const float*)d_in[6 + 10 * l];
        ha.b1[l]    = (const float*)d_in[7 + 10 * l];
        ha.E[l]     = ESa[l];
        ha.bstart[l] = bs;
        bs += (ESa[l] + 256 * 32 - 1) / (256 * 32);
    }
    ha.bstart[5] = bs;
    ha.H = Hp;

    WArgs wa{};
    for (int l = 0; l < 5; l++) {
        wa.w2[l]   = (const float*)d_in[8 + 10 * l];
        wa.b2[l]   = (const float*)d_in[9 + 10 * l];
        wa.cico[l] = CIa[l] * COa[l];
        wa.E[l]    = ESa[l];
    }
    wa.H  = Hp;
    wa.sq = (float*)(wsw + sqO);

    // ---- K2..K6 (unchanged from round 15) ----
    countA_k<<<TILES0 + TILES1 + histBlocks + bs, 256, 0, stream>>>(
        sa, ha, (const int*)d_in[3], (const int*)d_in[13],
        wsw + MO, wsw + M1O, histBlocks);
    scanP1_k<<<NB0 + NB1 + btiles, 256, 0, stream>>>(
        sa, sx, wsw + MO, wsw + M2O, wsw + ctO,
        wsw + M1O, wsw + M21O, wsw + ct1O);
    scanP2_k<<<3, 512, 0, stream>>>(sa, sx, wsw + ctO, wsw + bsO,
                                    wsw + ct1O, wsw + bs1O);
    scanP3_k<<<btiles + TILES0 + TILES1, 256, 0, stream>>>(
        sa, sx,
        (const int*)d_in[2], (const int*)d_in[3], (const float*)d_in[4],
        x0, wsw + M2O, wsw + bsO, pay2,
        (const float*)d_in[6], (const float*)d_in[7], Hp,
        (const int*)d_in[12], (const int*)d_in[13], (const float*)d_in[14],
        wsw + M21O, wsw + bs1O, pay1);

    float* yb = (float*)(wsw + yO);

    scatC_k<<<histBlocks + NB0 + 5 + NB1, 256, 0, stream>>>(
        sa, wa, histBlocks, pay2, wsw + bsO,
        (const float*)d_in[8], (const float*)d_in[9],
        (const float*)d_in[10], (const float*)d_in[11], x0, yb,
        pay1, wsw + bs1O, wsw + rpO[1], rec1);

    // ---- mega: whole level pipeline + fc ----
    MegaArgs ma{};
    for (int l = 0; l < 5; l++) {
        ma.crp[l]  = wsw + crpO[l];
        ma.cnid[l] = wsw + cnidO[l];
        ma.src[l]   = (const int*)d_in[2 + 10 * l];
        ma.eattr[l] = (const float*)d_in[4 + 10 * l];
        ma.w1[l]   = (const float*)d_in[6 + 10 * l];
        ma.b1[l]   = (const float*)d_in[7 + 10 * l];
        ma.w2[l]   = (const float*)d_in[8 + 10 * l];
        ma.b2[l]   = (const float*)d_in[9 + 10 * l];
        ma.root[l] = (const float*)d_in[10 + 10 * l];
        ma.bias[l] = (const float*)d_in[11 + 10 * l];
        ma.xn[l] = (float*)(wsw + xnO[l]);
        ma.pn[l] = (float*)(wsw + pnO[l]);
    }
    ma.rp[1] = wsw + rpO[1];
    for (int l = 2; l < 5; l++) { ma.rp[l] = wsw + rpO[l]; ma.eid[l] = wsw + eidO[l]; }
    ma.rec1 = rec1;
    ma.pos0 = pos0;
    ma.y    = yb;
    ma.fc_w = (const float*)d_in[52];
    ma.fc_b = (const float*)d_in[53];
    ma.sq   = wa.sq;
    ma.out  = (float*)d_out;
    ma.bar  = wsw + barO;

    mega_k<<<MBLK, 256, 0, stream>>>(ma);
}